// Round 17
// baseline (319.828 us; speedup 1.0000x reference)
//
#include <hip/hip_runtime.h>
#include <cstddef>
#include <cstdint>

#define SQ 2048
#define DH 256
#define NH 8
#define BATCH 4
#define MROWS (BATCH*SQ)   // 8192
#define HID (NH*DH)        // 2048

typedef __attribute__((ext_vector_type(8)))  short bf16x8;
typedef __attribute__((ext_vector_type(16))) float f32x16;

typedef __attribute__((address_space(1))) const unsigned char gbuf_t;
typedef __attribute__((address_space(3))) unsigned char lbuf_t;

__device__ __forceinline__ void gl_lds16(const void* g, void* l) {
  // async global->LDS, 16B per lane; LDS dest is wave-uniform base + lane*16
  __builtin_amdgcn_global_load_lds((gbuf_t*)g, (lbuf_t*)l, 16, 0, 0);
}

__device__ __forceinline__ unsigned short f2bf(float f) {
  unsigned u = __float_as_uint(f);
  unsigned r = (u + 0x7FFFu + ((u >> 16) & 1u)) >> 16;   // RNE
  return (unsigned short)r;
}
__device__ __forceinline__ unsigned pk2(float a, float b) {
  return (unsigned)f2bf(a) | ((unsigned)f2bf(b) << 16);
}
__device__ __forceinline__ float fexp2(float x) {   // raw v_exp_f32 (2^x)
  float r;
  asm("v_exp_f32 %0, %1" : "=v"(r) : "v"(x));
  return r;
}
__device__ __forceinline__ f32x16 zero16() {
  f32x16 v;
#pragma unroll
  for (int i = 0; i < 16; ++i) v[i] = 0.0f;
  return v;
}

// ===================== Kernel 0: fp32 -> bf16 conversion =====================
__global__ void __launch_bounds__(256) cvt_kernel(
    const float* __restrict__ X,  const float* __restrict__ Wq,
    const float* __restrict__ Wk, const float* __restrict__ Wv,
    const float* __restrict__ Wo,
    unsigned short* __restrict__ Xb,  unsigned short* __restrict__ Wqb,
    unsigned short* __restrict__ Wkb, unsigned short* __restrict__ Wvb,
    unsigned short* __restrict__ Wob)
{
  int bid = blockIdx.x;
  const float* src; unsigned short* dst; size_t off;
  if      (bid < 512) { src = X;  dst = Xb;  off = (size_t)bid * 4096; }
  else if (bid < 640) { src = Wq; dst = Wqb; off = (size_t)(bid - 512) * 4096; }
  else if (bid < 768) { src = Wk; dst = Wkb; off = (size_t)(bid - 640) * 4096; }
  else if (bid < 896) { src = Wv; dst = Wvb; off = (size_t)(bid - 768) * 4096; }
  else                { src = Wo; dst = Wob; off = (size_t)(bid - 896) * 4096; }
  int tid = threadIdx.x;
#pragma unroll
  for (int k = 0; k < 4; ++k) {
    size_t idx = off + ((size_t)k * 256 + tid) * 4;
    float4 v = *(const float4*)(src + idx);
    uint2 o; o.x = pk2(v.x, v.y); o.y = pk2(v.z, v.w);
    *(uint2*)(dst + idx) = o;
  }
}

// ===================== Kernel 1: fused QKV projection (bf16 MFMA) =====================
// R14-verified: K=256 in 2 chunks of 128; 64KB LDS -> 2 blocks/CU.
__global__ void __launch_bounds__(256, 2) qkv_kernel(
    const unsigned short* __restrict__ Xbf,
    const unsigned short* __restrict__ Wqb,
    const unsigned short* __restrict__ Wkb,
    const unsigned short* __restrict__ Wvb,
    const float* __restrict__ bq, const float* __restrict__ bk, const float* __restrict__ bv,
    unsigned short* __restrict__ q_ws, unsigned short* __restrict__ k_ws,
    unsigned short* __restrict__ vt_ws)
{
  __shared__ unsigned char TA[32768];   // [128 rows][256B], byte ^= (row&15)<<4
  __shared__ unsigned char TB[32768];
  const int tid = threadIdx.x, w = tid >> 6, l = tid & 63;
  const int h = l >> 5, t = l & 31;
  const int wm = w >> 1, wn = w & 1;
  const int z = blockIdx.z;
  const int m0 = (z == 2) ? blockIdx.y * 128 : blockIdx.x * 128;
  const int n0 = (z == 2) ? blockIdx.x * 128 : blockIdx.y * 128;
  const unsigned short* Asrc = (z == 2) ? Wvb : Xbf;
  const unsigned short* Bsrc = (z == 0) ? Wqb : (z == 1) ? Wkb : Xbf;

  const int rowo = l >> 4;            // 0..3 within 4-row group (1KB)
  const int bin  = (l & 15) * 16;     // byte-in-row (256B rows)
  const int swz  = (t & 15) << 4;

  f32x16 acc00 = zero16(), acc01 = zero16(), acc10 = zero16(), acc11 = zero16();

  for (int chunk = 0; chunk < 2; ++chunk) {
    __syncthreads();   // previous chunk fully consumed
#pragma unroll
    for (int i2 = 0; i2 < 8; ++i2) {
      int j = 8 * w + i2;            // 0..31 (1KB groups)
      int row = 4 * j + rowo;        // 0..127
      gl_lds16((const unsigned char*)(Asrc + (size_t)(m0 + row) * 256 + chunk * 128)
                 + (bin ^ ((row & 15) << 4)),
               &TA[j * 1024]);
    }
#pragma unroll
    for (int i2 = 0; i2 < 8; ++i2) {
      int j = 8 * w + i2;
      int row = 4 * j + rowo;
      gl_lds16((const unsigned char*)(Bsrc + (size_t)(n0 + row) * 256 + chunk * 128)
                 + (bin ^ ((row & 15) << 4)),
               &TB[j * 1024]);
    }
    __syncthreads();   // chunk resident
#pragma unroll
    for (int kc = 0; kc < 8; ++kc) {
      int kb = (32 * kc + 16 * h) ^ swz;
      bf16x8 a0 = *(const bf16x8*)&TA[(size_t)(64 * wm + t) * 256 + kb];
      bf16x8 a1 = *(const bf16x8*)&TA[(size_t)(64 * wm + 32 + t) * 256 + kb];
      bf16x8 b0 = *(const bf16x8*)&TB[(size_t)(64 * wn + t) * 256 + kb];
      bf16x8 b1 = *(const bf16x8*)&TB[(size_t)(64 * wn + 32 + t) * 256 + kb];
      acc00 = __builtin_amdgcn_mfma_f32_32x32x16_bf16(a0, b0, acc00, 0, 0, 0);
      acc01 = __builtin_amdgcn_mfma_f32_32x32x16_bf16(a0, b1, acc01, 0, 0, 0);
      acc10 = __builtin_amdgcn_mfma_f32_32x32x16_bf16(a1, b0, acc10, 0, 0, 0);
      acc11 = __builtin_amdgcn_mfma_f32_32x32x16_bf16(a1, b1, acc11, 0, 0, 0);
    }
  }

  if (z < 2) {
    unsigned short* outp = z ? k_ws : q_ws;
    const float* bias = z ? bk : bq;
    float bn0 = bias[n0 + 64 * wn + t];
    float bn1 = bias[n0 + 64 * wn + 32 + t];
#pragma unroll
    for (int mt = 0; mt < 2; ++mt) {
#pragma unroll
      for (int nt = 0; nt < 2; ++nt) {
        int n = n0 + 64 * wn + 32 * nt + t;
        int headn = n >> 8, d = n & 255;
        float bb = nt ? bn1 : bn0;
        const f32x16& A = (mt == 0) ? (nt == 0 ? acc00 : acc01) : (nt == 0 ? acc10 : acc11);
#pragma unroll
        for (int r = 0; r < 16; ++r) {
          int m = m0 + 64 * wm + 32 * mt + (r & 3) + 8 * (r >> 2) + 4 * h;
          int batch = m >> 11, s = m & 2047;
          outp[(((size_t)batch * NH + headn) * SQ + s) * DH + d] = f2bf(A[r] + bb);
        }
      }
    }
  } else {
#pragma unroll
    for (int mt = 0; mt < 2; ++mt) {
#pragma unroll
      for (int r = 0; r < 16; ++r) {
        int j = m0 + 64 * wm + 32 * mt + (r & 3) + 8 * (r >> 2) + 4 * h;
        float bj = bv[j];
        int headj = j >> 8, jl = j & 255;
#pragma unroll
        for (int nt = 0; nt < 2; ++nt) {
          int sall = n0 + 64 * wn + 32 * nt + t;
          int batch = sall >> 11, ss = sall & 2047;
          const f32x16& A = (mt == 0) ? (nt == 0 ? acc00 : acc01) : (nt == 0 ? acc10 : acc11);
          vt_ws[((size_t)batch * NH + headj) * DH * SQ + (size_t)jl * SQ + ss] = f2bf(A[r] + bj);
        }
      }
    }
  }
}

// ===================== Kernel 2: flash attention — KVBLK=32, 4-wave, dbuf, 2 blocks/CU =====================
// Completes the structure matrix: {2 blocks/CU + dbuf + prefetch}. 4 waves x 32 q-rows
// (q-tile 128), KVBLK=32, KT[2][16K]+VT[2][16K]+MB[8K] = 72KB -> 2 blocks/CU.
// Waves on a SIMD come from DIFFERENT blocks -> free-running drift covers stalls while
// the R10 pipeline (prefetch t+1 under compute t, 1 barrier/tile) covers staging.
// QK^T split into two independent 8-deep MFMA chains (accumulate-latency insurance).
__global__ void __launch_bounds__(256, 2) attn_kernel(
    const unsigned short* __restrict__ q_ws,
    const unsigned short* __restrict__ k_ws,
    const unsigned short* __restrict__ vt_ws,
    const int* __restrict__ mask,
    unsigned short* __restrict__ o_ws)
{
  __shared__ unsigned char KT[2][16384];  // [32 keys][512B], byte ^= (row&15)<<4
  __shared__ unsigned char VT[2][16384];  // [256 d][64B],    byte ^= (row&3)<<4
  __shared__ float MB[2048];              // mask bias for this batch (0 / -1e9)

  const int tid = threadIdx.x, w = tid >> 6, l = tid & 63;   // w = 0..3
  const int h = l >> 5, t = l & 31;
  const int bid = blockIdx.x;
  const int xcd = bid & 7, slot = bid >> 3;   // 512 blocks: 4 bh x 16 q-tiles per XCD
  const int bh = xcd * 4 + (slot >> 4);
  const int qt = slot & 15;
  const int b = bh >> 3, head = bh & 7;
  const int q0 = qt * 128;

  const float SC2 = 0.0625f * 1.44269504f;   // score scale * log2(e)
  const float THR = 11.54f;                   // 8 * log2(e)

  {
    const int* mrow = mask + b * SQ;
    for (int i = tid; i < SQ; i += 256) MB[i] = mrow[i] ? 0.0f : -1.0e9f;
  }

  const unsigned short* kplane = k_ws + (size_t)bh * SQ * DH;
  const unsigned short* vplane = vt_ws + (size_t)bh * DH * SQ;

  // Q fragments (B operand: col=q=t, k=d contiguous); wave owns q-rows q0+32w..+31
  bf16x8 qf[16];
  {
    const unsigned short* qb = q_ws + ((size_t)bh * SQ + (q0 + 32 * w + t)) * DH + 8 * h;
#pragma unroll
    for (int kc = 0; kc < 16; ++kc) qf[kc] = *(const bf16x8*)(qb + 16 * kc);
  }

  const int krow_o = l >> 5, kcol = (l & 31) * 16;   // K rows 512B
  const int vrow_o = l >> 2, vcol = (l & 3) * 16;    // V rows 64B

  // prologue: stage tile 0 into buf 0
  {
#pragma unroll
    for (int i = 0; i < 4; ++i) {
      int j = 4 * w + i;                 // 0..15, 1KB groups (2 K-rows each)
      int row = 2 * j + krow_o;          // 0..31
      gl_lds16((const unsigned char*)(kplane + (size_t)row * DH) + (kcol ^ ((row & 15) << 4)),
               &KT[0][j * 1024]);
    }
#pragma unroll
    for (int i = 0; i < 4; ++i) {
      int j = 4 * w + i;                 // 0..15, 1KB groups (16 V-rows each)
      int row = 16 * j + vrow_o;         // 0..255
      gl_lds16((const unsigned char*)(vplane + (size_t)row * SQ) + (vcol ^ ((row & 3) << 4)),
               &VT[0][j * 1024]);
    }
  }
  __syncthreads();   // drains vmcnt -> tile 0 resident (also covers MB)

  f32x16 o[8];
#pragma unroll
  for (int i = 0; i < 8; ++i) o[i] = zero16();
  float m_run = -3.0e38f, l_run = 0.0f;

  const int swzK = (t & 15) << 4;
  const int swzV = (t & 3) << 4;

  int cur = 0;
  for (int kb = 0; kb < SQ; kb += 32) {
    const int nxt = cur ^ 1;
    // ---- issue prefetch of tile t+1 (lands at end-of-tile barrier) ----
    if (kb + 32 < SQ) {
#pragma unroll
      for (int i = 0; i < 4; ++i) {
        int j = 4 * w + i;
        int row = 2 * j + krow_o;
        gl_lds16((const unsigned char*)(kplane + (size_t)(kb + 32 + row) * DH) + (kcol ^ ((row & 15) << 4)),
                 &KT[nxt][j * 1024]);
      }
#pragma unroll
      for (int i = 0; i < 4; ++i) {
        int j = 4 * w + i;
        int row = 16 * j + vrow_o;
        gl_lds16((const unsigned char*)(vplane + (size_t)row * SQ + kb + 32) + (vcol ^ ((row & 3) << 4)),
                 &VT[nxt][j * 1024]);
      }
    }

    // ---- QK^T (swapped): S^T[key][q], two independent 8-deep chains ----
    f32x16 sa = zero16(), sb = zero16();
    __builtin_amdgcn_s_setprio(1);
#pragma unroll
    for (int kc = 0; kc < 8; ++kc) {
      int kbbA = (32 * (2 * kc) + 16 * h) ^ swzK;
      int kbbB = (32 * (2 * kc + 1) + 16 * h) ^ swzK;
      bf16x8 a0 = *(const bf16x8*)&KT[cur][(size_t)t * 512 + kbbA];
      bf16x8 a1 = *(const bf16x8*)&KT[cur][(size_t)t * 512 + kbbB];
      sa = __builtin_amdgcn_mfma_f32_32x32x16_bf16(a0, qf[2 * kc], sa, 0, 0, 0);
      sb = __builtin_amdgcn_mfma_f32_32x32x16_bf16(a1, qf[2 * kc + 1], sb, 0, 0, 0);
    }
    __builtin_amdgcn_s_setprio(0);

    // ---- combine chains + mask + scale (log2 domain) ----
#pragma unroll
    for (int g = 0; g < 4; ++g) {
      float4 m0v = *(const float4*)&MB[kb + 4 * h + 8 * g];
      sa[4*g+0] = (sa[4*g+0] + sb[4*g+0]) * SC2 + m0v.x;
      sa[4*g+1] = (sa[4*g+1] + sb[4*g+1]) * SC2 + m0v.y;
      sa[4*g+2] = (sa[4*g+2] + sb[4*g+2]) * SC2 + m0v.z;
      sa[4*g+3] = (sa[4*g+3] + sb[4*g+3]) * SC2 + m0v.w;
    }
    // pairwise max tree (depth 4)
    f32x16 mm = sa;
#pragma unroll
    for (int s = 8; s >= 1; s >>= 1) {
#pragma unroll
      for (int r = 0; r < 8; ++r) {
        if (r < s) mm[r] = fmaxf(mm[r], mm[r + s]);
      }
    }
    float tm = fmaxf(mm[0], __shfl_xor(mm[0], 32, 64));

    // T13 defer-max: rescale only when the tile max overflows the threshold
    if (__builtin_expect(!__all(tm <= m_run + THR), 0)) {
      float m_new = fmaxf(m_run, tm);
      float rf = fexp2(m_run - m_new);
      m_run = m_new;
      l_run *= rf;
#pragma unroll
      for (int r = 0; r < 16; ++r) {
        float rr = __shfl(rf, (r & 3) + 8 * (r >> 2) + 4 * h, 64);
#pragma unroll
        for (int db = 0; db < 8; ++db) o[db][r] *= rr;
      }
    }

    // ---- fused softmax-slice ∥ PV: per 8-key slice (ks=0,1), exp+pack then 8 MFMAs ----
    float ssum = 0.0f;
#pragma unroll
    for (int ks = 0; ks < 2; ++ks) {
      const int base = 8 * ks;
      float e0 = fexp2(sa[base + 0] - m_run);
      float e1 = fexp2(sa[base + 1] - m_run);
      float e2 = fexp2(sa[base + 2] - m_run);
      float e3 = fexp2(sa[base + 3] - m_run);
      float e4 = fexp2(sa[base + 4] - m_run);
      float e5 = fexp2(sa[base + 5] - m_run);
      float e6 = fexp2(sa[base + 6] - m_run);
      float e7 = fexp2(sa[base + 7] - m_run);
      unsigned lo0, lo1, hi0, hi1;
      asm("v_cvt_pk_bf16_f32 %0, %1, %2" : "=v"(lo0) : "v"(e0), "v"(e1));
      asm("v_cvt_pk_bf16_f32 %0, %1, %2" : "=v"(lo1) : "v"(e2), "v"(e3));
      asm("v_cvt_pk_bf16_f32 %0, %1, %2" : "=v"(hi0) : "v"(e4), "v"(e5));
      asm("v_cvt_pk_bf16_f32 %0, %1, %2" : "=v"(hi1) : "v"(e6), "v"(e7));
      unsigned s0 = h ? lo0 : hi0;
      unsigned s1 = h ? lo1 : hi1;
      unsigned x0 = (unsigned)__shfl_xor((int)s0, 32, 64);
      unsigned x1 = (unsigned)__shfl_xor((int)s1, 32, 64);
      union { unsigned u[4]; bf16x8 v; } pu;
      pu.u[0] = h ? x0 : lo0;
      pu.u[1] = h ? x1 : lo1;
      pu.u[2] = h ? hi0 : x0;
      pu.u[3] = h ? hi1 : x1;
      bf16x8 pav = pu.v;
      ssum += ((e0 + e1) + (e2 + e3)) + ((e4 + e5) + (e6 + e7));
      __builtin_amdgcn_s_setprio(1);
#pragma unroll
      for (int db = 0; db < 8; ++db) {
        bf16x8 bv = *(const bf16x8*)&VT[cur][(size_t)(32 * db + t) * 64 + ((32 * ks + 16 * h) ^ swzV)];
        o[db] = __builtin_amdgcn_mfma_f32_32x32x16_bf16(pav, bv, o[db], 0, 0, 0);
      }
      __builtin_amdgcn_s_setprio(0);
    }
    float ls = ssum + __shfl_xor(ssum, 32, 64);
    l_run += ls;

    __syncthreads();   // drains prefetch vmcnt; tile t+1 resident in [nxt]
    cur = nxt;
  }

  // epilogue: normalize, write bf16 [8192][2048] (row = b*2048+s, col = head*256+d)
  float linv = 1.0f / l_run;
  unsigned short* ob = o_ws + (size_t)b * SQ * HID + (size_t)head * DH;
#pragma unroll
  for (int r = 0; r < 16; ++r) {
    int rowr = (r & 3) + 8 * (r >> 2) + 4 * h;
    float li = __shfl(linv, rowr, 64);
    int s = q0 + 32 * w + rowr;
    unsigned short* orow = ob + (size_t)s * HID;
#pragma unroll
    for (int db = 0; db < 8; ++db)
      orow[32 * db + t] = f2bf(o[db][r] * li);
  }
}

// ========== Kernel 3: FUSED out-projection + bias + residual + LayerNorm ==========
// R14-verified: double-buffered TA/TB (73KB -> 2 blocks/CU), prefetch-before-compute.
__global__ void __launch_bounds__(256, 2) oproj_ln_kernel(
    const unsigned short* __restrict__ Abf,
    const unsigned short* __restrict__ Wob,
    const float* __restrict__ bo, const float* __restrict__ Xin,
    const float* __restrict__ g, const float* __restrict__ be,
    float* __restrict__ out)
{
  __shared__ unsigned char TA[2][4096];    // [32 m][128B], byte ^= (row&7)<<4
  __shared__ unsigned char TB[2][32768];   // [256 n][128B]
  __shared__ float RS1[4][32], RS2[4][32];
  const int tid = threadIdx.x, w = tid >> 6, l = tid & 63;
  const int h = l >> 5, t = l & 31;
  const int m0 = blockIdx.x * 32;
  const int arow_o = l >> 3, ab_in = (l & 7) * 16;
  const int swz = (t & 7) << 4;

  // prologue: stage chunk 0 into buf 0
  {
    int row = 8 * w + arow_o;
    gl_lds16((const unsigned char*)(Abf + (size_t)(m0 + row) * HID) + (ab_in ^ ((row & 7) << 4)),
             &TA[0][w * 1024]);
#pragma unroll
    for (int i2 = 0; i2 < 8; ++i2) {
      int j = 8 * w + i2;
      int row2 = 8 * j + arow_o;
      gl_lds16((const unsigned char*)(Wob + (size_t)row2 * HID) + (ab_in ^ ((row2 & 7) << 4)),
               &TB[0][j * 1024]);
    }
  }
  __syncthreads();

  f32x16 acc0 = zero16(), acc1 = zero16();
  int cur = 0;
  for (int chunk = 0; chunk < 32; ++chunk) {
    const int nxt = cur ^ 1;
    // issue prefetch of chunk+1
    if (chunk + 1 < 32) {
      int row = 8 * w + arow_o;
      gl_lds16((const unsigned char*)(Abf + (size_t)(m0 + row) * HID + (chunk + 1) * 64) + (ab_in ^ ((row & 7) << 4)),
               &TA[nxt][w * 1024]);
#pragma unroll
      for (int i2 = 0; i2 < 8; ++i2) {
        int j = 8 * w + i2;
        int row2 = 8 * j + arow_o;
        gl_lds16((const unsigned char*)(Wob + (size_t)row2 * HID + (chunk + 1) * 64) + (ab_in ^ ((row2 & 7) << 4)),
                 &TB[nxt][j * 1024]);
      }
    }
    // compute chunk from buf[cur]
#pragma unroll
    for (int kc = 0; kc < 4; ++kc) {
      int kbb = (32 * kc + 16 * h) ^ swz;
      bf16x8 a  = *(const bf16x8*)&TA[cur][(size_t)t * 128 + kbb];
      bf16x8 b0 = *(const bf16x8*)&TB[cur][(size_t)(64 * w + t) * 128 + kbb];
      bf16x8 b1 = *(const bf16x8*)&TB[cur][(size_t)(64 * w + 32 + t) * 128 + kbb];
      acc0 = __builtin_amdgcn_mfma_f32_32x32x16_bf16(a, b0, acc0, 0, 0, 0);
      acc1 = __builtin_amdgcn_mfma_f32_32x32x16_bf16(a, b1, acc1, 0, 0, 0);
    }
    __syncthreads();   // drains prefetch; chunk+1 resident
    cur = nxt;
  }

  // bias + residual in place
  const int c0 = 64 * w + t, c1 = 64 * w + 32 + t;
  float bb0 = bo[c0], bb1 = bo[c1];
  float gc0 = g[c0],  gc1 = g[c1];
  float bc0 = be[c0], bc1 = be[c1];
#pragma unroll
  for (int r = 0; r < 16; ++r) {
    int row = m0 + (r & 3) + 8 * (r >> 2) + 4 * h;
    acc0[r] += bb0 + Xin[(size_t)row * DH + c0];
    acc1[r] += bb1 + Xin[(size_t)row * DH + c1];
  }

  // per-row partial sums over this wave's 64 cols (reduce within 32-lane half)
#pragma unroll
  for (int r = 0; r < 16; ++r) {
    float p1 = acc0[r] + acc1[r];
    float p2 = acc0[r] * acc0[r] + acc1[r] * acc1[r];
#pragma unroll
    for (int off = 1; off < 32; off <<= 1) {
      p1 += __shfl_xor(p1, off, 64);
      p2 += __shfl_xor(p2, off, 64);
    }
    if (t == 0) {
      int rl = (r & 3) + 8 * (r >> 2) + 4 * h;
      RS1[w][rl] = p1; RS2[w][rl] = p2;
    }
  }
  __syncthreads();

  // combine 4 waves, normalize, store
#pragma unroll
  for (int r = 0; r < 16; ++r) {
    int rl = (r & 3) + 8 * (r >> 2) + 4 * h;
    float s1 = (RS1[0][rl] + RS1[1][rl]) + (RS1[2][rl] + RS1[3][rl]);
    float s2 = (RS2[0][rl] + RS2[1][rl]) + (RS2[2][rl] + RS2[3][rl]);
    float mean = s1 * (1.0f / 256.0f);
    float var  = s2 * (1.0f / 256.0f) - mean * mean;
    float rstd = rsqrtf(var + 1e-5f);
    size_t rowo = (size_t)(m0 + rl) * DH;
    out[rowo + c0] = (acc0[r] - mean) * rstd * gc0 + bc0;
    out[rowo + c1] = (acc1[r] - mean) * rstd * gc1 + bc1;
  }
}

// ===================== launch =====================
extern "C" void kernel_launch(void* const* d_in, const int* in_sizes, int n_in,
                              void* d_out, int out_size, void* d_ws, size_t ws_size,
                              hipStream_t stream) {
  const float* Q    = (const float*)d_in[0];
  const int*   mask = (const int*)  d_in[1];
  const float* WQ_w = (const float*)d_in[2];
  const float* WQ_b = (const float*)d_in[3];
  const float* WK_w = (const float*)d_in[4];
  const float* WK_b = (const float*)d_in[5];
  const float* WV_w = (const float*)d_in[6];
  const float* WV_b = (const float*)d_in[7];
  const float* WO_w = (const float*)d_in[8];
  const float* WO_b = (const float*)d_in[9];
  const float* ln_g = (const float*)d_in[10];
  const float* ln_b = (const float*)d_in[11];
  float* out = (float*)d_out;

  uint8_t* ws = (uint8_t*)d_ws;
  const size_t MB1 = 1048576;
  unsigned short* Xb   = (unsigned short*)(ws + 0 * MB1);    // 4 MB
  unsigned short* Wqb  = (unsigned short*)(ws + 4 * MB1);    // 1 MB
  unsigned short* Wkb  = (unsigned short*)(ws + 5 * MB1);
  unsigned short* Wvb  = (unsigned short*)(ws + 6 * MB1);
  unsigned short* Wob  = (unsigned short*)(ws + 7 * MB1);
  unsigned short* q_ws = (unsigned short*)(ws + 8 * MB1);    // 32 MB
  unsigned short* k_ws = (unsigned short*)(ws + 40 * MB1);   // 32 MB
  unsigned short* vtws = (unsigned short*)(ws + 72 * MB1);   // 32 MB
  unsigned short* o_ws = (unsigned short*)(ws + 104 * MB1);  // 32 MB

  cvt_kernel<<<1024, 256, 0, stream>>>(Q, WQ_w, WK_w, WV_w, WO_w, Xb, Wqb, Wkb, Wvb, Wob);
  qkv_kernel<<<dim3(64, 16, 3), 256, 0, stream>>>(Xb, Wqb, Wkb, Wvb, WQ_b, WK_b, WV_b,
                                                  q_ws, k_ws, vtws);
  attn_kernel<<<dim3(512), 256, 0, stream>>>(q_ws, k_ws, vtws, mask, o_ws);
  oproj_ln_kernel<<<dim3(256), 256, 0, stream>>>(o_ws, Wob, WO_b, Q, ln_g, ln_b, out);
}

// Round 18
// 283.287 us; speedup vs baseline: 1.1290x; 1.1290x over previous
//
#include <hip/hip_runtime.h>
#include <cstddef>
#include <cstdint>

#define SQ 2048
#define DH 256
#define NH 8
#define BATCH 4
#define MROWS (BATCH*SQ)   // 8192
#define HID (NH*DH)        // 2048

typedef __attribute__((ext_vector_type(8)))  short bf16x8;
typedef __attribute__((ext_vector_type(16))) float f32x16;

typedef __attribute__((address_space(1))) const unsigned char gbuf_t;
typedef __attribute__((address_space(3))) unsigned char lbuf_t;

__device__ __forceinline__ void gl_lds16(const void* g, void* l) {
  // async global->LDS, 16B per lane; LDS dest is wave-uniform base + lane*16
  __builtin_amdgcn_global_load_lds((gbuf_t*)g, (lbuf_t*)l, 16, 0, 0);
}

__device__ __forceinline__ unsigned short f2bf(float f) {
  unsigned u = __float_as_uint(f);
  unsigned r = (u + 0x7FFFu + ((u >> 16) & 1u)) >> 16;   // RNE
  return (unsigned short)r;
}
__device__ __forceinline__ unsigned pk2(float a, float b) {
  return (unsigned)f2bf(a) | ((unsigned)f2bf(b) << 16);
}
__device__ __forceinline__ float fexp2(float x) {   // raw v_exp_f32 (2^x)
  float r;
  asm("v_exp_f32 %0, %1" : "=v"(r) : "v"(x));
  return r;
}
__device__ __forceinline__ f32x16 zero16() {
  f32x16 v;
#pragma unroll
  for (int i = 0; i < 16; ++i) v[i] = 0.0f;
  return v;
}

// ===================== Kernel 0: fp32 -> bf16 conversion =====================
__global__ void __launch_bounds__(256) cvt_kernel(
    const float* __restrict__ X,  const float* __restrict__ Wq,
    const float* __restrict__ Wk, const float* __restrict__ Wv,
    const float* __restrict__ Wo,
    unsigned short* __restrict__ Xb,  unsigned short* __restrict__ Wqb,
    unsigned short* __restrict__ Wkb, unsigned short* __restrict__ Wvb,
    unsigned short* __restrict__ Wob)
{
  int bid = blockIdx.x;
  const float* src; unsigned short* dst; size_t off;
  if      (bid < 512) { src = X;  dst = Xb;  off = (size_t)bid * 4096; }
  else if (bid < 640) { src = Wq; dst = Wqb; off = (size_t)(bid - 512) * 4096; }
  else if (bid < 768) { src = Wk; dst = Wkb; off = (size_t)(bid - 640) * 4096; }
  else if (bid < 896) { src = Wv; dst = Wvb; off = (size_t)(bid - 768) * 4096; }
  else                { src = Wo; dst = Wob; off = (size_t)(bid - 896) * 4096; }
  int tid = threadIdx.x;
#pragma unroll
  for (int k = 0; k < 4; ++k) {
    size_t idx = off + ((size_t)k * 256 + tid) * 4;
    float4 v = *(const float4*)(src + idx);
    uint2 o; o.x = pk2(v.x, v.y); o.y = pk2(v.z, v.w);
    *(uint2*)(dst + idx) = o;
  }
}

// ===================== Kernel 1: fused QKV projection (bf16 MFMA) =====================
// R14-verified: K=256 in 2 chunks of 128; 64KB LDS -> 2 blocks/CU.
__global__ void __launch_bounds__(256, 2) qkv_kernel(
    const unsigned short* __restrict__ Xbf,
    const unsigned short* __restrict__ Wqb,
    const unsigned short* __restrict__ Wkb,
    const unsigned short* __restrict__ Wvb,
    const float* __restrict__ bq, const float* __restrict__ bk, const float* __restrict__ bv,
    unsigned short* __restrict__ q_ws, unsigned short* __restrict__ k_ws,
    unsigned short* __restrict__ vt_ws)
{
  __shared__ unsigned char TA[32768];   // [128 rows][256B], byte ^= (row&15)<<4
  __shared__ unsigned char TB[32768];
  const int tid = threadIdx.x, w = tid >> 6, l = tid & 63;
  const int h = l >> 5, t = l & 31;
  const int wm = w >> 1, wn = w & 1;
  const int z = blockIdx.z;
  const int m0 = (z == 2) ? blockIdx.y * 128 : blockIdx.x * 128;
  const int n0 = (z == 2) ? blockIdx.x * 128 : blockIdx.y * 128;
  const unsigned short* Asrc = (z == 2) ? Wvb : Xbf;
  const unsigned short* Bsrc = (z == 0) ? Wqb : (z == 1) ? Wkb : Xbf;

  const int rowo = l >> 4;            // 0..3 within 4-row group (1KB)
  const int bin  = (l & 15) * 16;     // byte-in-row (256B rows)
  const int swz  = (t & 15) << 4;

  f32x16 acc00 = zero16(), acc01 = zero16(), acc10 = zero16(), acc11 = zero16();

  for (int chunk = 0; chunk < 2; ++chunk) {
    __syncthreads();   // previous chunk fully consumed
#pragma unroll
    for (int i2 = 0; i2 < 8; ++i2) {
      int j = 8 * w + i2;            // 0..31 (1KB groups)
      int row = 4 * j + rowo;        // 0..127
      gl_lds16((const unsigned char*)(Asrc + (size_t)(m0 + row) * 256 + chunk * 128)
                 + (bin ^ ((row & 15) << 4)),
               &TA[j * 1024]);
    }
#pragma unroll
    for (int i2 = 0; i2 < 8; ++i2) {
      int j = 8 * w + i2;
      int row = 4 * j + rowo;
      gl_lds16((const unsigned char*)(Bsrc + (size_t)(n0 + row) * 256 + chunk * 128)
                 + (bin ^ ((row & 15) << 4)),
               &TB[j * 1024]);
    }
    __syncthreads();   // chunk resident
#pragma unroll
    for (int kc = 0; kc < 8; ++kc) {
      int kb = (32 * kc + 16 * h) ^ swz;
      bf16x8 a0 = *(const bf16x8*)&TA[(size_t)(64 * wm + t) * 256 + kb];
      bf16x8 a1 = *(const bf16x8*)&TA[(size_t)(64 * wm + 32 + t) * 256 + kb];
      bf16x8 b0 = *(const bf16x8*)&TB[(size_t)(64 * wn + t) * 256 + kb];
      bf16x8 b1 = *(const bf16x8*)&TB[(size_t)(64 * wn + 32 + t) * 256 + kb];
      acc00 = __builtin_amdgcn_mfma_f32_32x32x16_bf16(a0, b0, acc00, 0, 0, 0);
      acc01 = __builtin_amdgcn_mfma_f32_32x32x16_bf16(a0, b1, acc01, 0, 0, 0);
      acc10 = __builtin_amdgcn_mfma_f32_32x32x16_bf16(a1, b0, acc10, 0, 0, 0);
      acc11 = __builtin_amdgcn_mfma_f32_32x32x16_bf16(a1, b1, acc11, 0, 0, 0);
    }
  }

  if (z < 2) {
    unsigned short* outp = z ? k_ws : q_ws;
    const float* bias = z ? bk : bq;
    float bn0 = bias[n0 + 64 * wn + t];
    float bn1 = bias[n0 + 64 * wn + 32 + t];
#pragma unroll
    for (int mt = 0; mt < 2; ++mt) {
#pragma unroll
      for (int nt = 0; nt < 2; ++nt) {
        int n = n0 + 64 * wn + 32 * nt + t;
        int headn = n >> 8, d = n & 255;
        float bb = nt ? bn1 : bn0;
        const f32x16& A = (mt == 0) ? (nt == 0 ? acc00 : acc01) : (nt == 0 ? acc10 : acc11);
#pragma unroll
        for (int r = 0; r < 16; ++r) {
          int m = m0 + 64 * wm + 32 * mt + (r & 3) + 8 * (r >> 2) + 4 * h;
          int batch = m >> 11, s = m & 2047;
          outp[(((size_t)batch * NH + headn) * SQ + s) * DH + d] = f2bf(A[r] + bb);
        }
      }
    }
  } else {
#pragma unroll
    for (int mt = 0; mt < 2; ++mt) {
#pragma unroll
      for (int r = 0; r < 16; ++r) {
        int j = m0 + 64 * wm + 32 * mt + (r & 3) + 8 * (r >> 2) + 4 * h;
        float bj = bv[j];
        int headj = j >> 8, jl = j & 255;
#pragma unroll
        for (int nt = 0; nt < 2; ++nt) {
          int sall = n0 + 64 * wn + 32 * nt + t;
          int batch = sall >> 11, ss = sall & 2047;
          const f32x16& A = (mt == 0) ? (nt == 0 ? acc00 : acc01) : (nt == 0 ? acc10 : acc11);
          vt_ws[((size_t)batch * NH + headj) * DH * SQ + (size_t)jl * SQ + ss] = f2bf(A[r] + bj);
        }
      }
    }
  }
}

// ===================== Kernel 2: flash attention — R10-exact (229 us verified) =====================
// 8 waves x 32 q-rows, KVBLK=64, dbuf K/V, prefetch at loop top, QK^T, tree max,
// defer-max, fused slice softmax∥PV, ONE barrier at end of tile.
__global__ void __launch_bounds__(512, 2) attn_kernel(
    const unsigned short* __restrict__ q_ws,
    const unsigned short* __restrict__ k_ws,
    const unsigned short* __restrict__ vt_ws,
    const int* __restrict__ mask,
    unsigned short* __restrict__ o_ws)
{
  __shared__ unsigned char KT[2][32768];  // [64 keys][512B], byte ^= (row&15)<<4
  __shared__ unsigned char VT[2][32768];  // [256 d][128B],   byte ^= (row&7)<<4
  __shared__ float MB[2048];              // mask bias for this batch (0 / -1e9)

  const int tid = threadIdx.x, w = tid >> 6, l = tid & 63;
  const int h = l >> 5, t = l & 31;
  const int bid = blockIdx.x;
  const int xcd = bid & 7, slot = bid >> 3;
  const int bh = xcd * 4 + (slot >> 3);
  const int qt = slot & 7;
  const int b = bh >> 3, head = bh & 7;
  const int q0 = qt * 256;

  const float SC2 = 0.0625f * 1.44269504f;   // score scale * log2(e)
  const float THR = 11.54f;                   // 8 * log2(e)

  {
    const int* mrow = mask + b * SQ;
    for (int i = tid; i < SQ; i += 512) MB[i] = mrow[i] ? 0.0f : -1.0e9f;
  }

  const unsigned short* kplane = k_ws + (size_t)bh * SQ * DH;
  const unsigned short* vplane = vt_ws + (size_t)bh * DH * SQ;

  // Q fragments (B operand: col=q=t, k=d contiguous)
  bf16x8 qf[16];
  {
    const unsigned short* qb = q_ws + ((size_t)bh * SQ + (q0 + 32 * w + t)) * DH + 8 * h;
#pragma unroll
    for (int kc = 0; kc < 16; ++kc) qf[kc] = *(const bf16x8*)(qb + 16 * kc);
  }

  const int krow_o = l >> 5, kcol = (l & 31) * 16;
  const int vrow_o = l >> 3, vcol = (l & 7) * 16;

  // prologue: stage tile 0 into buf 0
  {
#pragma unroll
    for (int i = 0; i < 4; ++i) {
      int j = 4 * w + i;
      int row = 2 * j + krow_o;
      gl_lds16((const unsigned char*)(kplane + (size_t)row * DH) + (kcol ^ ((row & 15) << 4)),
               &KT[0][j * 1024]);
    }
#pragma unroll
    for (int i = 0; i < 4; ++i) {
      int j = 4 * w + i;
      int row = 8 * j + vrow_o;
      gl_lds16((const unsigned char*)(vplane + (size_t)row * SQ) + (vcol ^ ((row & 7) << 4)),
               &VT[0][j * 1024]);
    }
  }
  __syncthreads();   // drains vmcnt -> tile 0 resident (also covers MB)

  f32x16 o[8];
#pragma unroll
  for (int i = 0; i < 8; ++i) o[i] = zero16();
  float m_run = -3.0e38f, l_run = 0.0f;

  const int swzK = (t & 15) << 4;
  const int swzV = (t & 7) << 4;

  int cur = 0;
  for (int kb = 0; kb < SQ; kb += 64) {
    const int nxt = cur ^ 1;
    // ---- issue prefetch of tile t+1 (lands at end-of-tile barrier) ----
    if (kb + 64 < SQ) {
#pragma unroll
      for (int i = 0; i < 4; ++i) {
        int j = 4 * w + i;
        int row = 2 * j + krow_o;
        gl_lds16((const unsigned char*)(kplane + (size_t)(kb + 64 + row) * DH) + (kcol ^ ((row & 15) << 4)),
                 &KT[nxt][j * 1024]);
      }
#pragma unroll
      for (int i = 0; i < 4; ++i) {
        int j = 4 * w + i;
        int row = 8 * j + vrow_o;
        gl_lds16((const unsigned char*)(vplane + (size_t)row * SQ + kb + 64) + (vcol ^ ((row & 7) << 4)),
                 &VT[nxt][j * 1024]);
      }
    }

    // ---- QK^T (swapped): S^T[key][q] ----
    f32x16 sa0 = zero16(), sa1 = zero16();
    __builtin_amdgcn_s_setprio(1);
#pragma unroll
    for (int kc = 0; kc < 16; ++kc) {
      int kbb = (32 * kc + 16 * h) ^ swzK;
      bf16x8 a0 = *(const bf16x8*)&KT[cur][(size_t)t * 512 + kbb];
      bf16x8 a1 = *(const bf16x8*)&KT[cur][(size_t)(32 + t) * 512 + kbb];
      sa0 = __builtin_amdgcn_mfma_f32_32x32x16_bf16(a0, qf[kc], sa0, 0, 0, 0);
      sa1 = __builtin_amdgcn_mfma_f32_32x32x16_bf16(a1, qf[kc], sa1, 0, 0, 0);
    }
    __builtin_amdgcn_s_setprio(0);

    // ---- mask + scale (log2 domain) + max tree ----
#pragma unroll
    for (int g = 0; g < 4; ++g) {
      float4 m0v = *(const float4*)&MB[kb + 4 * h + 8 * g];
      float4 m1v = *(const float4*)&MB[kb + 32 + 4 * h + 8 * g];
      sa0[4*g+0] = sa0[4*g+0] * SC2 + m0v.x;
      sa0[4*g+1] = sa0[4*g+1] * SC2 + m0v.y;
      sa0[4*g+2] = sa0[4*g+2] * SC2 + m0v.z;
      sa0[4*g+3] = sa0[4*g+3] * SC2 + m0v.w;
      sa1[4*g+0] = sa1[4*g+0] * SC2 + m1v.x;
      sa1[4*g+1] = sa1[4*g+1] * SC2 + m1v.y;
      sa1[4*g+2] = sa1[4*g+2] * SC2 + m1v.z;
      sa1[4*g+3] = sa1[4*g+3] * SC2 + m1v.w;
    }
    f32x16 mm;
#pragma unroll
    for (int r = 0; r < 16; ++r) mm[r] = fmaxf(sa0[r], sa1[r]);
#pragma unroll
    for (int s = 8; s >= 1; s >>= 1) {
#pragma unroll
      for (int r = 0; r < 8; ++r) {
        if (r < s) mm[r] = fmaxf(mm[r], mm[r + s]);
      }
    }
    float tm = fmaxf(mm[0], __shfl_xor(mm[0], 32, 64));

    // T13 defer-max: rescale only when the tile max overflows the threshold
    if (__builtin_expect(!__all(tm <= m_run + THR), 0)) {
      float m_new = fmaxf(m_run, tm);
      float rf = fexp2(m_run - m_new);
      m_run = m_new;
      l_run *= rf;
#pragma unroll
      for (int r = 0; r < 16; ++r) {
        float rr = __shfl(rf, (r & 3) + 8 * (r >> 2) + 4 * h, 64);
#pragma unroll
        for (int db = 0; db < 8; ++db) o[db][r] *= rr;
      }
    }

    // ---- fused softmax-slice ∥ PV: per 8-key slice, exp+pack then 8 MFMAs ----
    float ssum = 0.0f;
#pragma unroll
    for (int ks = 0; ks < 4; ++ks) {
      const f32x16& P = (ks < 2) ? sa0 : sa1;
      const int base = 8 * (ks & 1);
      float e0 = fexp2(P[base + 0] - m_run);
      float e1 = fexp2(P[base + 1] - m_run);
      float e2 = fexp2(P[base + 2] - m_run);
      float e3 = fexp2(P[base + 3] - m_run);
      float e4 = fexp2(P[base + 4] - m_run);
      float e5 = fexp2(P[base + 5] - m_run);
      float e6 = fexp2(P[base + 6] - m_run);
      float e7 = fexp2(P[base + 7] - m_run);
      unsigned lo0, lo1, hi0, hi1;
      asm("v_cvt_pk_bf16_f32 %0, %1, %2" : "=v"(lo0) : "v"(e0), "v"(e1));
      asm("v_cvt_pk_bf16_f32 %0, %1, %2" : "=v"(lo1) : "v"(e2), "v"(e3));
      asm("v_cvt_pk_bf16_f32 %0, %1, %2" : "=v"(hi0) : "v"(e4), "v"(e5));
      asm("v_cvt_pk_bf16_f32 %0, %1, %2" : "=v"(hi1) : "v"(e6), "v"(e7));
      unsigned s0 = h ? lo0 : hi0;
      unsigned s1 = h ? lo1 : hi1;
      unsigned x0 = (unsigned)__shfl_xor((int)s0, 32, 64);
      unsigned x1 = (unsigned)__shfl_xor((int)s1, 32, 64);
      union { unsigned u[4]; bf16x8 v; } pu;
      pu.u[0] = h ? x0 : lo0;
      pu.u[1] = h ? x1 : lo1;
      pu.u[2] = h ? hi0 : x0;
      pu.u[3] = h ? hi1 : x1;
      bf16x8 pav = pu.v;
      ssum += ((e0 + e1) + (e2 + e3)) + ((e4 + e5) + (e6 + e7));
      __builtin_amdgcn_s_setprio(1);
#pragma unroll
      for (int db = 0; db < 8; ++db) {
        bf16x8 bv = *(const bf16x8*)&VT[cur][(size_t)(32 * db + t) * 128 + ((32 * ks + 16 * h) ^ swzV)];
        o[db] = __builtin_amdgcn_mfma_f32_32x32x16_bf16(pav, bv, o[db], 0, 0, 0);
      }
      __builtin_amdgcn_s_setprio(0);
    }
    float ls = ssum + __shfl_xor(ssum, 32, 64);
    l_run += ls;

    __syncthreads();   // drains prefetch vmcnt; tile t+1 resident in [nxt]
    cur = nxt;
  }

  // epilogue: normalize, write bf16 [8192][2048] (row = b*2048+s, col = head*256+d)
  float linv = 1.0f / l_run;
  unsigned short* ob = o_ws + (size_t)b * SQ * HID + (size_t)head * DH;
#pragma unroll
  for (int r = 0; r < 16; ++r) {
    int rowr = (r & 3) + 8 * (r >> 2) + 4 * h;
    float li = __shfl(linv, rowr, 64);
    int s = q0 + 32 * w + rowr;
    unsigned short* orow = ob + (size_t)s * HID;
#pragma unroll
    for (int db = 0; db < 8; ++db)
      orow[32 * db + t] = f2bf(o[db][r] * li);
  }
}

// ========== Kernel 3: FUSED out-projection + bias + residual + LayerNorm ==========
// R14-verified: double-buffered TA/TB (73KB -> 2 blocks/CU), prefetch-before-compute.
__global__ void __launch_bounds__(256, 2) oproj_ln_kernel(
    const unsigned short* __restrict__ Abf,
    const unsigned short* __restrict__ Wob,
    const float* __restrict__ bo, const float* __restrict__ Xin,
    const float* __restrict__ g, const float* __restrict__ be,
    float* __restrict__ out)
{
  __shared__ unsigned char TA[2][4096];    // [32 m][128B], byte ^= (row&7)<<4
  __shared__ unsigned char TB[2][32768];   // [256 n][128B]
  __shared__ float RS1[4][32], RS2[4][32];
  const int tid = threadIdx.x, w = tid >> 6, l = tid & 63;
  const int h = l >> 5, t = l & 31;
  const int m0 = blockIdx.x * 32;
  const int arow_o = l >> 3, ab_in = (l & 7) * 16;
  const int swz = (t & 7) << 4;

  // prologue: stage chunk 0 into buf 0
  {
    int row = 8 * w + arow_o;
    gl_lds16((const unsigned char*)(Abf + (size_t)(m0 + row) * HID) + (ab_in ^ ((row & 7) << 4)),
             &TA[0][w * 1024]);
#pragma unroll
    for (int i2 = 0; i2 < 8; ++i2) {
      int j = 8 * w + i2;
      int row2 = 8 * j + arow_o;
      gl_lds16((const unsigned char*)(Wob + (size_t)row2 * HID) + (ab_in ^ ((row2 & 7) << 4)),
               &TB[0][j * 1024]);
    }
  }
  __syncthreads();

  f32x16 acc0 = zero16(), acc1 = zero16();
  int cur = 0;
  for (int chunk = 0; chunk < 32; ++chunk) {
    const int nxt = cur ^ 1;
    // issue prefetch of chunk+1
    if (chunk + 1 < 32) {
      int row = 8 * w + arow_o;
      gl_lds16((const unsigned char*)(Abf + (size_t)(m0 + row) * HID + (chunk + 1) * 64) + (ab_in ^ ((row & 7) << 4)),
               &TA[nxt][w * 1024]);
#pragma unroll
      for (int i2 = 0; i2 < 8; ++i2) {
        int j = 8 * w + i2;
        int row2 = 8 * j + arow_o;
        gl_lds16((const unsigned char*)(Wob + (size_t)row2 * HID + (chunk + 1) * 64) + (ab_in ^ ((row2 & 7) << 4)),
                 &TB[nxt][j * 1024]);
      }
    }
    // compute chunk from buf[cur]
#pragma unroll
    for (int kc = 0; kc < 4; ++kc) {
      int kbb = (32 * kc + 16 * h) ^ swz;
      bf16x8 a  = *(const bf16x8*)&TA[cur][(size_t)t * 128 + kbb];
      bf16x8 b0 = *(const bf16x8*)&TB[cur][(size_t)(64 * w + t) * 128 + kbb];
      bf16x8 b1 = *(const bf16x8*)&TB[cur][(size_t)(64 * w + 32 + t) * 128 + kbb];
      acc0 = __builtin_amdgcn_mfma_f32_32x32x16_bf16(a, b0, acc0, 0, 0, 0);
      acc1 = __builtin_amdgcn_mfma_f32_32x32x16_bf16(a, b1, acc1, 0, 0, 0);
    }
    __syncthreads();   // drains prefetch; chunk+1 resident
    cur = nxt;
  }

  // bias + residual in place
  const int c0 = 64 * w + t, c1 = 64 * w + 32 + t;
  float bb0 = bo[c0], bb1 = bo[c1];
  float gc0 = g[c0],  gc1 = g[c1];
  float bc0 = be[c0], bc1 = be[c1];
#pragma unroll
  for (int r = 0; r < 16; ++r) {
    int row = m0 + (r & 3) + 8 * (r >> 2) + 4 * h;
    acc0[r] += bb0 + Xin[(size_t)row * DH + c0];
    acc1[r] += bb1 + Xin[(size_t)row * DH + c1];
  }

  // per-row partial sums over this wave's 64 cols (reduce within 32-lane half)
#pragma unroll
  for (int r = 0; r < 16; ++r) {
    float p1 = acc0[r] + acc1[r];
    float p2 = acc0[r] * acc0[r] + acc1[r] * acc1[r];
#pragma unroll
    for (int off = 1; off < 32; off <<= 1) {
      p1 += __shfl_xor(p1, off, 64);
      p2 += __shfl_xor(p2, off, 64);
    }
    if (t == 0) {
      int rl = (r & 3) + 8 * (r >> 2) + 4 * h;
      RS1[w][rl] = p1; RS2[w][rl] = p2;
    }
  }
  __syncthreads();

  // combine 4 waves, normalize, store
#pragma unroll
  for (int r = 0; r < 16; ++r) {
    int rl = (r & 3) + 8 * (r >> 2) + 4 * h;
    float s1 = (RS1[0][rl] + RS1[1][rl]) + (RS1[2][rl] + RS1[3][rl]);
    float s2 = (RS2[0][rl] + RS2[1][rl]) + (RS2[2][rl] + RS2[3][rl]);
    float mean = s1 * (1.0f / 256.0f);
    float var  = s2 * (1.0f / 256.0f) - mean * mean;
    float rstd = rsqrtf(var + 1e-5f);
    size_t rowo = (size_t)(m0 + rl) * DH;
    out[rowo + c0] = (acc0[r] - mean) * rstd * gc0 + bc0;
    out[rowo + c1] = (acc1[r] - mean) * rstd * gc1 + bc1;
  }
}

// ===================== launch =====================
extern "C" void kernel_launch(void* const* d_in, const int* in_sizes, int n_in,
                              void* d_out, int out_size, void* d_ws, size_t ws_size,
                              hipStream_t stream) {
  const float* Q    = (const float*)d_in[0];
  const int*   mask = (const int*)  d_in[1];
  const float* WQ_w = (const float*)d_in[2];
  const float* WQ_b = (const float*)d_in[3];
  const float* WK_w = (const float*)d_in[4];
  const float* WK_b = (const float*)d_in[5];
  const float* WV_w = (const float*)d_in[6];
  const float* WV_b = (const float*)d_in[7];
  const float* WO_w = (const float*)d_in[8];
  const float* WO_b = (const float*)d_in[9];
  const float* ln_g = (const float*)d_in[10];
  const float* ln_b = (const float*)d_in[11];
  float* out = (float*)d_out;

  uint8_t* ws = (uint8_t*)d_ws;
  const size_t MB1 = 1048576;
  unsigned short* Xb   = (unsigned short*)(ws + 0 * MB1);    // 4 MB
  unsigned short* Wqb  = (unsigned short*)(ws + 4 * MB1);    // 1 MB
  unsigned short* Wkb  = (unsigned short*)(ws + 5 * MB1);
  unsigned short* Wvb  = (unsigned short*)(ws + 6 * MB1);
  unsigned short* Wob  = (unsigned short*)(ws + 7 * MB1);
  unsigned short* q_ws = (unsigned short*)(ws + 8 * MB1);    // 32 MB
  unsigned short* k_ws = (unsigned short*)(ws + 40 * MB1);   // 32 MB
  unsigned short* vtws = (unsigned short*)(ws + 72 * MB1);   // 32 MB
  unsigned short* o_ws = (unsigned short*)(ws + 104 * MB1);  // 32 MB

  cvt_kernel<<<1024, 256, 0, stream>>>(Q, WQ_w, WK_w, WV_w, WO_w, Xb, Wqb, Wkb, Wvb, Wob);
  qkv_kernel<<<dim3(64, 16, 3), 256, 0, stream>>>(Xb, Wqb, Wkb, Wvb, WQ_b, WK_b, WV_b,
                                                  q_ws, k_ws, vtws);
  attn_kernel<<<dim3(256), 512, 0, stream>>>(q_ws, k_ws, vtws, mask, o_ws);
  oproj_ln_kernel<<<dim3(256), 256, 0, stream>>>(o_ws, Wob, WO_b, Q, ln_g, ln_b, out);
}